// Round 2
// baseline (3123.451 us; speedup 1.0000x reference)
//
#include <hip/hip_runtime.h>
#include <math.h>

#define HW   96
#define LPIX 9216      // 96*96
#define CDIM 128

static constexpr float kScale = 0.17677669529663687f;  // 1/sqrt(32)

// ---------------------------------------------------------------------------
// conv3x3 (pad 1) + BN-scale + bias + ReLU.  NCHW.
// grid: (36 spatial tiles of 16x16, 16 co-groups of 8, B). block 256.
// Stages 4 input channels per barrier pair (was 1) to cut barrier count 4x.
// ---------------------------------------------------------------------------
template <int CIN>
__global__ __launch_bounds__(256) void conv3x3_bn_relu(
    const float* __restrict__ in, const float* __restrict__ w,
    const float* __restrict__ gamma, const float* __restrict__ beta,
    float* __restrict__ out)
{
    const int tile = blockIdx.x;
    const int cg   = blockIdx.y;
    const int b    = blockIdx.z;
    const int y0   = (tile / 6) * 16;
    const int x0   = (tile % 6) * 16;
    const int tid  = threadIdx.x;
    const int ty   = tid >> 4;
    const int tx   = tid & 15;

    __shared__ float sIn[4][18 * 20];   // 4 ci planes, 18x18 tile, pitch 20

    float acc[8];
#pragma unroll
    for (int o = 0; o < 8; ++o) acc[o] = 0.f;

    const float* inb = in + ((size_t)b * CIN) * (HW * HW);

    for (int cc = 0; cc < CIN; cc += 4) {
        // stage 4 planes: 4*324 = 1296 elements
        for (int i = tid; i < 1296; i += 256) {
            int c  = i / 324;
            int rc = i - c * 324;
            int r  = rc / 18, col = rc - r * 18;
            int gy = y0 - 1 + r, gx = x0 - 1 + col;
            float v = 0.f;
            if (gy >= 0 && gy < HW && gx >= 0 && gx < HW)
                v = inb[(size_t)(cc + c) * (HW * HW) + gy * HW + gx];
            sIn[c][r * 20 + col] = v;
        }
        __syncthreads();
#pragma unroll
        for (int c = 0; c < 4; ++c) {
            // block-uniform weight indices -> scalar loads
            const float* wp = w + ((size_t)(cg * 8) * CIN + cc + c) * 9;
#pragma unroll
            for (int ki = 0; ki < 3; ++ki) {
#pragma unroll
                for (int kj = 0; kj < 3; ++kj) {
                    float v = sIn[c][(ty + ki) * 20 + tx + kj];
#pragma unroll
                    for (int o = 0; o < 8; ++o)
                        acc[o] = fmaf(v, wp[(size_t)o * CIN * 9 + ki * 3 + kj], acc[o]);
                }
            }
        }
        __syncthreads();
    }

    const int y = y0 + ty, x = x0 + tx;
    const float rs = rsqrtf(1.f + 1e-5f);
#pragma unroll
    for (int o = 0; o < 8; ++o) {
        int co   = cg * 8 + o;
        float sc = gamma[co] * rs;
        float r  = fmaf(acc[o], sc, beta[co]);
        out[(((size_t)b * CDIM + co) * HW + y) * HW + x] = fmaxf(r, 0.f);
    }
}

// ---------------------------------------------------------------------------
// per-pixel 128->128 linear (1x1 conv) + bias.  in/out layout [b, c, l].
// grid: (36 pixel tiles of 256, 4 co-groups of 32, B). block 256.
// ---------------------------------------------------------------------------
__global__ __launch_bounds__(256) void linear128(
    const float* __restrict__ in, const float* __restrict__ w,
    const float* __restrict__ bias, float* __restrict__ out)
{
    const int pt  = blockIdx.x;
    const int cg  = blockIdx.y;
    const int b   = blockIdx.z;
    const int tid = threadIdx.x;
    const int l0  = pt * 256;

    __shared__ float sIn[32 * 256];

    float acc[32];
#pragma unroll
    for (int o = 0; o < 32; ++o) acc[o] = 0.f;

    const float* inb = in + (size_t)b * CDIM * LPIX + l0;

    for (int cc = 0; cc < 128; cc += 32) {
        __syncthreads();
        for (int i = 0; i < 32; ++i)
            sIn[i * 256 + tid] = inb[(size_t)(cc + i) * LPIX + tid];
        __syncthreads();
#pragma unroll
        for (int ii = 0; ii < 32; ii += 8) {
            float v[8];
#pragma unroll
            for (int k = 0; k < 8; ++k) v[k] = sIn[(ii + k) * 256 + tid];
#pragma unroll
            for (int o = 0; o < 32; ++o) {
                const float* wr = w + (size_t)(cg * 32 + o) * 128 + cc + ii;
#pragma unroll
                for (int k = 0; k < 8; ++k) acc[o] = fmaf(v[k], wr[k], acc[o]);
            }
        }
    }
#pragma unroll
    for (int o = 0; o < 32; ++o) {
        int co = cg * 32 + o;
        out[((size_t)b * CDIM + co) * LPIX + l0 + tid] = acc[o] + bias[co];
    }
}

// ---------------------------------------------------------------------------
// attn logits (324x128 per pixel) + bias + scale + softmax over q(9).
// writes A in layout [b, h, p, q, L]  (q-planes: coalesced 64B segments).
// grid: (288 pixel tiles of 32, B). block 576 = 36 rows (h,p) x 16 lanes,
// each thread handles 2 pixels.
// ---------------------------------------------------------------------------
__global__ __launch_bounds__(576) void attn_softmax(
    const float* __restrict__ fg, const float* __restrict__ aw,
    const float* __restrict__ ab, float* __restrict__ out)
{
    const int bt  = blockIdx.x;
    const int b   = blockIdx.y;
    const int l0  = bt * 32;
    const int tid = threadIdx.x;
    const int r   = tid >> 4;   // 0..35 = h*9+p
    const int u   = tid & 15;

    __shared__ float sW[324 * 32];
    __shared__ float sF[32 * 36];   // [px][ci-chunk] pitch 36 (conflict-free f4)

    float lg0[9], lg1[9];
#pragma unroll
    for (int q = 0; q < 9; ++q) { lg0[q] = 0.f; lg1[q] = 0.f; }

    for (int cc = 0; cc < 128; cc += 32) {
        __syncthreads();
        for (int i = tid; i < 324 * 32; i += 576)
            sW[i] = aw[(size_t)(i >> 5) * 128 + cc + (i & 31)];
        for (int i = tid; i < 1024; i += 576) {
            int ci = i >> 5, px = i & 31;
            sF[px * 36 + ci] = fg[((size_t)b * CDIM + cc + ci) * LPIX + l0 + px];
        }
        __syncthreads();

        float4 fA[8], fB[8];
#pragma unroll
        for (int k = 0; k < 8; ++k) {
            fA[k] = *(const float4*)&sF[u * 36 + k * 4];
            fB[k] = *(const float4*)&sF[(u + 16) * 36 + k * 4];
        }
        const int obase = r * 9;
#pragma unroll
        for (int q = 0; q < 9; ++q) {
            const float4* wr = (const float4*)&sW[(obase + q) * 32];
            float s0 = 0.f, s1 = 0.f;
#pragma unroll
            for (int k = 0; k < 8; ++k) {
                float4 wv = wr[k];
                s0 += wv.x * fA[k].x + wv.y * fA[k].y + wv.z * fA[k].z + wv.w * fA[k].w;
                s1 += wv.x * fB[k].x + wv.y * fB[k].y + wv.z * fB[k].z + wv.w * fB[k].w;
            }
            lg0[q] += s0;
            lg1[q] += s1;
        }
    }

    const int obase = r * 9;
    float bs[9];
#pragma unroll
    for (int q = 0; q < 9; ++q) bs[q] = ab[obase + q];

    // out layout [b, h(4), p(9), q(9), L]; r = h*9+p so plane index = r*9+q
    float* outb = out + ((size_t)b * 36 + r) * 9 * (size_t)LPIX;

    {
        float m = -1e30f;
#pragma unroll
        for (int q = 0; q < 9; ++q) { lg0[q] = (lg0[q] + bs[q]) * kScale; m = fmaxf(m, lg0[q]); }
        float s = 0.f;
#pragma unroll
        for (int q = 0; q < 9; ++q) { lg0[q] = __expf(lg0[q] - m); s += lg0[q]; }
        float inv = 1.f / s;
#pragma unroll
        for (int q = 0; q < 9; ++q) outb[(size_t)q * LPIX + l0 + u] = lg0[q] * inv;
    }
    {
        float m = -1e30f;
#pragma unroll
        for (int q = 0; q < 9; ++q) { lg1[q] = (lg1[q] + bs[q]) * kScale; m = fmaxf(m, lg1[q]); }
        float s = 0.f;
#pragma unroll
        for (int q = 0; q < 9; ++q) { lg1[q] = __expf(lg1[q] - m); s += lg1[q]; }
        float inv = 1.f / s;
#pragma unroll
        for (int q = 0; q < 9; ++q) outb[(size_t)q * LPIX + l0 + u + 16] = lg1[q] * inv;
    }
}

// ---------------------------------------------------------------------------
// fused einsum + fold: folded[b,c,y,x] = sum_{oy,ox in 5x5} S[oy,ox]*v[c,y+oy-2,x+ox-2]
// with S[oy,ox] = sum over (p,q) with q-k offset == (oy,ox), l'(p) in bounds,
// of A[b,h,p,q,l'(p)]   (A layout now [b,h,p,q,L]).
// grid: (288 tiles of 8x4, B). block 128 = 4 heads x (4y x 8x) pixels.
// ---------------------------------------------------------------------------
__global__ __launch_bounds__(128) void attn_fold(
    const float* __restrict__ A, const float* __restrict__ v,
    float* __restrict__ out)
{
    const int tile = blockIdx.x;            // 0..287
    const int b    = blockIdx.y;
    const int y0   = (tile / 12) * 4;
    const int x0   = (tile % 12) * 8;
    const int tid  = threadIdx.x;
    const int h    = tid >> 5;
    const int py   = (tid >> 3) & 3;
    const int px   = tid & 7;

    __shared__ float sV[96 * 132];   // [spatial 8x12][c pitch 132]

    for (int i = tid; i < 96 * 128; i += 128) {
        int c = i / 96, s = i - c * 96;
        int sy = s / 12, sx = s - sy * 12;
        int gy = y0 - 2 + sy, gx = x0 - 2 + sx;
        float val = 0.f;
        if (gy >= 0 && gy < HW && gx >= 0 && gx < HW)
            val = v[(((size_t)b * CDIM + c) * HW + gy) * HW + gx];
        sV[s * 132 + c] = val;
    }
    __syncthreads();

    const int y = y0 + py, x = x0 + px;

    float S[25];
#pragma unroll
    for (int i = 0; i < 25; ++i) S[i] = 0.f;

    const float* Ab = A + ((size_t)(b * 4 + h) * 81) * (size_t)LPIX;
#pragma unroll
    for (int ki = 0; ki < 3; ++ki) {
        int ly = y + 1 - ki;
        bool vy = (ly >= 0 && ly < HW);
#pragma unroll
        for (int kj = 0; kj < 3; ++kj) {
            int lx = x + 1 - kj;
            if (vy && lx >= 0 && lx < HW) {
                const float* Ap = Ab + (size_t)(ki * 3 + kj) * 9 * (size_t)LPIX
                                + ly * HW + lx;
#pragma unroll
                for (int q = 0; q < 9; ++q) {
                    int qi = q / 3, qj = q - qi * 3;
                    S[(qi - ki + 2) * 5 + (qj - kj + 2)] += Ap[(size_t)q * LPIX];
                }
            }
        }
    }

    float4 acc[8];
#pragma unroll
    for (int k = 0; k < 8; ++k) acc[k] = make_float4(0.f, 0.f, 0.f, 0.f);

#pragma unroll
    for (int oy = 0; oy < 5; ++oy) {
#pragma unroll
        for (int ox = 0; ox < 5; ++ox) {
            float sc = S[oy * 5 + ox];
            const float4* vr =
                (const float4*)&sV[((py + oy) * 12 + px + ox) * 132 + h * 32];
#pragma unroll
            for (int k = 0; k < 8; ++k) {
                float4 vv = vr[k];
                acc[k].x = fmaf(sc, vv.x, acc[k].x);
                acc[k].y = fmaf(sc, vv.y, acc[k].y);
                acc[k].z = fmaf(sc, vv.z, acc[k].z);
                acc[k].w = fmaf(sc, vv.w, acc[k].w);
            }
        }
    }

    float* ob = out + (((size_t)b * CDIM + h * 32) * HW + y) * HW + x;
#pragma unroll
    for (int k = 0; k < 8; ++k) {
        ob[(size_t)(k * 4 + 0) * HW * HW] = acc[k].x;
        ob[(size_t)(k * 4 + 1) * HW * HW] = acc[k].y;
        ob[(size_t)(k * 4 + 2) * HW * HW] = acc[k].z;
        ob[(size_t)(k * 4 + 3) * HW * HW] = acc[k].w;
    }
}

// ---------------------------------------------------------------------------
extern "C" void kernel_launch(void* const* d_in, const int* in_sizes, int n_in,
                              void* d_out, int out_size, void* d_ws, size_t ws_size,
                              hipStream_t stream)
{
    const float* x    = (const float*)d_in[0];
    const float* fg   = (const float*)d_in[1];
    const float* c1w  = (const float*)d_in[2];
    const float* bn1g = (const float*)d_in[3];
    const float* bn1b = (const float*)d_in[4];
    const float* c2w  = (const float*)d_in[5];
    const float* bn2g = (const float*)d_in[6];
    const float* bn2b = (const float*)d_in[7];
    const float* vw   = (const float*)d_in[8];
    const float* vb   = (const float*)d_in[9];
    const float* aw   = (const float*)d_in[10];
    const float* abv  = (const float*)d_in[11];
    const float* pw   = (const float*)d_in[12];
    const float* pb   = (const float*)d_in[13];
    const float* c3w  = (const float*)d_in[14];
    const float* bn3g = (const float*)d_in[15];
    const float* bn3b = (const float*)d_in[16];
    const float* c4w  = (const float*)d_in[17];
    const float* bn4g = (const float*)d_in[18];
    const float* bn4b = (const float*)d_in[19];

    float* bufA = (float*)d_ws;                    // 9,437,184 floats
    float* bufB = bufA + (size_t)9437184;          // 9,437,184 floats
    float* bufD = bufB + (size_t)9437184;          // 23,887,872 floats (attn)

    dim3 cgrid(36, 16, 8);
    conv3x3_bn_relu<64><<<cgrid, 256, 0, stream>>>(x, c1w, bn1g, bn1b, bufA);
    conv3x3_bn_relu<128><<<cgrid, 256, 0, stream>>>(bufA, c2w, bn2g, bn2b, bufB);
    linear128<<<dim3(36, 4, 8), 256, 0, stream>>>(bufB, vw, vb, bufA);     // v
    attn_softmax<<<dim3(288, 8), 576, 0, stream>>>(fg, aw, abv, bufD);
    attn_fold<<<dim3(288, 8), 128, 0, stream>>>(bufD, bufA, bufB);         // folded
    linear128<<<dim3(36, 4, 8), 256, 0, stream>>>(bufB, pw, pb, bufA);     // proj
    conv3x3_bn_relu<128><<<cgrid, 256, 0, stream>>>(bufA, c3w, bn3g, bn3b, bufB);
    conv3x3_bn_relu<128><<<cgrid, 256, 0, stream>>>(bufB, c4w, bn4g, bn4b, (float*)d_out);
}

// Round 3
// 702.952 us; speedup vs baseline: 4.4433x; 4.4433x over previous
//
#include <hip/hip_runtime.h>
#include <math.h>

typedef __attribute__((ext_vector_type(8))) short short8;
typedef __attribute__((ext_vector_type(4))) float f32x4;
typedef unsigned short u16;
typedef unsigned int u32;

#define HW   96
#define LPIX 9216
static constexpr float kScale = 0.17677669529663687f;  // 1/sqrt(32)

__device__ inline u16 f2bf(float f) {
    u32 x = __float_as_uint(f);
    return (u16)((x + 0x7fffu + ((x >> 16) & 1u)) >> 16);   // RNE
}

// ---------------------------------------------------------------------------
// NCHW fp32 -> NHWC bf16 transpose-cast. grid (96 y, 8 b), block 256.
// ---------------------------------------------------------------------------
template <int C>
__global__ __launch_bounds__(256) void cast_nchw_nhwc(
    const float* __restrict__ in, u16* __restrict__ out)
{
    const int y = blockIdx.x, b = blockIdx.y, tid = threadIdx.x;
    __shared__ float sT[HW * C];
    for (int i = tid; i < HW * C; i += 256) {
        int c = i / HW, xx = i - c * HW;
        sT[xx * C + c] = in[(((size_t)b * C + c) * HW + y) * HW + xx];
    }
    __syncthreads();
    for (int i = tid; i < HW * (C / 8); i += 256) {
        int c8 = i % (C / 8), xx = i / (C / 8);
        union { short8 v8; u16 u[8]; } pk;
#pragma unroll
        for (int j = 0; j < 8; ++j) pk.u[j] = f2bf(sT[xx * C + c8 * 8 + j]);
        *(short8*)&out[(((size_t)b * HW + y) * HW + xx) * C + c8 * 8] = pk.v8;
    }
}

// ---------------------------------------------------------------------------
// conv weights [co 128][ci CIN][3][3] fp32 -> [f 9][ci/32][co 128][32] bf16
// ---------------------------------------------------------------------------
__global__ void cast_conv_w(const float* __restrict__ w, u16* __restrict__ wp, int CIN)
{
    int n = 9 * CIN * 128;
    int i = blockIdx.x * 256 + threadIdx.x;
    if (i >= n) return;
    int cil = i & 31; int t = i >> 5; int co = t & 127; int t2 = t >> 7;
    int nc5 = CIN >> 5;
    int c5 = t2 % nc5; int f = t2 / nc5;
    int ci = c5 * 32 + cil;
    wp[i] = f2bf(w[(size_t)(co * CIN + ci) * 9 + f]);
}

// dense matrix fp32 -> bf16 (same layout)
__global__ void cast_mat(const float* __restrict__ in, u16* __restrict__ out, int n)
{
    int i = blockIdx.x * 256 + threadIdx.x;
    if (i < n) out[i] = f2bf(in[i]);
}

// ---------------------------------------------------------------------------
// conv3x3 + BN + ReLU via MFMA implicit GEMM.
// in: NHWC bf16 [b][y][x][CIN]; wp: [9][CIN/32][128][32] bf16.
// out: OUT_F32 ? NCHW fp32 : NHWC bf16.
// grid (96 y, 8 b), block 256 (4 waves, 2x2 wave grid: M=64 x N=48 per wave).
// ---------------------------------------------------------------------------
template <int CIN, bool OUT_F32>
__global__ __launch_bounds__(256) void conv_mfma(
    const u16* __restrict__ in, const u16* __restrict__ wp,
    const float* __restrict__ g, const float* __restrict__ be, void* outv)
{
    constexpr int NC5 = CIN / 32;
    const int y0 = blockIdx.x, b = blockIdx.y;
    const int tid = threadIdx.x, lane = tid & 63, wv = tid >> 6;
    const int wm = wv >> 1, wn = wv & 1;
    const int lx = lane & 15, q = lane >> 4;

    __shared__ char smem[3 * 98 * 40 * 2 + 3 * 128 * 40 * 2];   // 54,240 B
    u16* sIn = (u16*)smem;                       // [ki 3][col 98][ci 32 pitch 40]
    u16* sW  = (u16*)(smem + 3 * 98 * 40 * 2);   // [kj 3][co 128][ci 32 pitch 40]
    float* sT = (float*)smem;                    // epilogue reuse [96 px][65]

    f32x4 acc[4][3];
#pragma unroll
    for (int mt = 0; mt < 4; ++mt)
#pragma unroll
        for (int nt = 0; nt < 3; ++nt) acc[mt][nt] = (f32x4){0.f, 0.f, 0.f, 0.f};

    for (int c5 = 0; c5 < NC5; ++c5) {
        for (int ki = 0; ki < 3; ++ki) {
            __syncthreads();   // previous readers done before overwriting LDS
            if (ki == 0) {
                // stage input chunk: 3 rows x 98 cols x 32 ci
                for (int i = tid; i < 1176; i += 256) {
                    int ci8 = i & 3, t = i >> 2, col = t % 98, kr = t / 98;
                    int gy = y0 - 1 + kr, gx = col - 1;
                    short8 v = {0, 0, 0, 0, 0, 0, 0, 0};
                    if (gy >= 0 && gy < HW && gx >= 0 && gx < HW)
                        v = *(const short8*)&in[(((size_t)b * HW + gy) * HW + gx) * CIN
                                                + c5 * 32 + ci8 * 8];
                    *(short8*)&sIn[(kr * 98 + col) * 40 + ci8 * 8] = v;
                }
            }
            // stage weights for 3 kj offsets of this ki
            for (int i = tid; i < 1536; i += 256) {
                int ci8 = i & 3, t = i >> 2, co = t & 127, kj = t >> 7;
                short8 v = *(const short8*)&wp[(size_t)((((ki * 3 + kj) * NC5 + c5) * 128 + co) * 32
                                                         + ci8 * 8)];
                *(short8*)&sW[(kj * 128 + co) * 40 + ci8 * 8] = v;
            }
            __syncthreads();
#pragma unroll
            for (int kj = 0; kj < 3; ++kj) {
                short8 af[4], bfr[3];
#pragma unroll
                for (int mt = 0; mt < 4; ++mt)
                    af[mt] = *(const short8*)&sW[(kj * 128 + wm * 64 + mt * 16 + lx) * 40 + q * 8];
#pragma unroll
                for (int nt = 0; nt < 3; ++nt) {
                    int col = wn * 48 + nt * 16 + lx + kj;   // input x = px + kj - 1
                    bfr[nt] = *(const short8*)&sIn[(ki * 98 + col) * 40 + q * 8];
                }
#pragma unroll
                for (int mt = 0; mt < 4; ++mt)
#pragma unroll
                    for (int nt = 0; nt < 3; ++nt)
                        acc[mt][nt] = __builtin_amdgcn_mfma_f32_16x16x32_bf16(
                            af[mt], bfr[nt], acc[mt][nt], 0, 0, 0);
            }
        }
    }

    const float rs = rsqrtf(1.f + 1e-5f);
    if (OUT_F32) {
        // direct NCHW fp32 store: C-layout cols (px) are lane-consecutive
        float* out = (float*)outv;
#pragma unroll
        for (int mt = 0; mt < 4; ++mt) {
#pragma unroll
            for (int reg = 0; reg < 4; ++reg) {
                int co = wm * 64 + mt * 16 + q * 4 + reg;
                float sc = g[co] * rs, bb = be[co];
#pragma unroll
                for (int nt = 0; nt < 3; ++nt) {
                    int px = wn * 48 + nt * 16 + lx;
                    out[(((size_t)b * 128 + co) * HW + y0) * HW + px] =
                        fmaxf(fmaf(acc[mt][nt][reg], sc, bb), 0.f);
                }
            }
        }
    } else {
        // LDS transpose epilogue -> NHWC bf16 contiguous-channel stores
        u16* out = (u16*)outv;
        for (int mh = 0; mh < 2; ++mh) {
            __syncthreads();
            if (wm == mh) {
#pragma unroll
                for (int mt = 0; mt < 4; ++mt)
#pragma unroll
                    for (int nt = 0; nt < 3; ++nt)
#pragma unroll
                        for (int reg = 0; reg < 4; ++reg)
                            sT[(wn * 48 + nt * 16 + lx) * 65 + mt * 16 + q * 4 + reg] =
                                acc[mt][nt][reg];
            }
            __syncthreads();
            for (int i = tid; i < 768; i += 256) {
                int cog = i & 7, px = i >> 3;
                union { short8 v8; u16 u[8]; } pk;
#pragma unroll
                for (int j = 0; j < 8; ++j) {
                    int co = mh * 64 + cog * 8 + j;
                    pk.u[j] = f2bf(fmaxf(fmaf(sT[px * 65 + cog * 8 + j], g[co] * rs, be[co]), 0.f));
                }
                *(short8*)&out[(((size_t)b * HW + y0) * HW + px) * 128 + mh * 64 + cog * 8] = pk.v8;
            }
        }
    }
}

// ---------------------------------------------------------------------------
// 128->128 linear + bias via MFMA. in/out NHWC-flat bf16 [b*L][128].
// grid 1152 (64 px per block), block 256 (2x2 waves: M=64 x N=32).
// ---------------------------------------------------------------------------
__global__ __launch_bounds__(256) void linear_mfma(
    const u16* __restrict__ in, const u16* __restrict__ wp,
    const float* __restrict__ bias, u16* __restrict__ out)
{
    const int l0 = blockIdx.x * 64;
    const int tid = threadIdx.x, lane = tid & 63, wv = tid >> 6;
    const int wm = wv >> 1, wn = wv & 1;
    const int lx = lane & 15, q = lane >> 4;

    __shared__ char smem[4 * 64 * 40 * 2 + 4 * 128 * 40 * 2];   // 61,440 B
    u16* sX = (u16*)smem;                        // [c4][px 64][32 pitch 40]
    u16* sW = (u16*)(smem + 4 * 64 * 40 * 2);    // [c4][co 128][32 pitch 40]
    float* sT = (float*)smem;                    // epilogue [64][65]

    for (int i = tid; i < 1024; i += 256) {
        int k8 = i & 15, px = i >> 4;
        short8 v = *(const short8*)&in[((size_t)(l0 + px)) * 128 + k8 * 8];
        *(short8*)&sX[((k8 >> 2) * 64 + px) * 40 + (k8 & 3) * 8] = v;
    }
    for (int i = tid; i < 2048; i += 256) {
        int k8 = i & 15, co = i >> 4;
        short8 v = *(const short8*)&wp[(size_t)co * 128 + k8 * 8];
        *(short8*)&sW[((k8 >> 2) * 128 + co) * 40 + (k8 & 3) * 8] = v;
    }
    __syncthreads();

    f32x4 acc[4][2];
#pragma unroll
    for (int mt = 0; mt < 4; ++mt)
#pragma unroll
        for (int nt = 0; nt < 2; ++nt) acc[mt][nt] = (f32x4){0.f, 0.f, 0.f, 0.f};

#pragma unroll
    for (int c4 = 0; c4 < 4; ++c4) {
        short8 af[4], bfr[2];
#pragma unroll
        for (int mt = 0; mt < 4; ++mt)
            af[mt] = *(const short8*)&sW[(c4 * 128 + wm * 64 + mt * 16 + lx) * 40 + q * 8];
#pragma unroll
        for (int nt = 0; nt < 2; ++nt)
            bfr[nt] = *(const short8*)&sX[(c4 * 64 + wn * 32 + nt * 16 + lx) * 40 + q * 8];
#pragma unroll
        for (int mt = 0; mt < 4; ++mt)
#pragma unroll
            for (int nt = 0; nt < 2; ++nt)
                acc[mt][nt] = __builtin_amdgcn_mfma_f32_16x16x32_bf16(
                    af[mt], bfr[nt], acc[mt][nt], 0, 0, 0);
    }

    for (int mh = 0; mh < 2; ++mh) {
        __syncthreads();
        if (wm == mh) {
#pragma unroll
            for (int mt = 0; mt < 4; ++mt)
#pragma unroll
                for (int nt = 0; nt < 2; ++nt)
#pragma unroll
                    for (int reg = 0; reg < 4; ++reg)
                        sT[(wn * 32 + nt * 16 + lx) * 65 + mt * 16 + q * 4 + reg] =
                            acc[mt][nt][reg];
        }
        __syncthreads();
        for (int i = tid; i < 512; i += 256) {
            int cog = i & 7, px = i >> 3;
            union { short8 v8; u16 u[8]; } pk;
#pragma unroll
            for (int j = 0; j < 8; ++j) {
                int co = mh * 64 + cog * 8 + j;
                pk.u[j] = f2bf(sT[px * 65 + cog * 8 + j] + bias[co]);
            }
            *(short8*)&out[((size_t)(l0 + px)) * 128 + mh * 64 + cog * 8] = pk.v8;
        }
    }
}

// ---------------------------------------------------------------------------
// attn logits + softmax, register-light (no LDS, no spill).
// 1 wave = 1 (h,p) row x 64 px; weights via wave-uniform scalar loads (fp32).
// fgb: NHWC bf16 [b][l][128]. A out: [b][h][p][q][L] fp32.
// grid (144 l-tiles, 4 h, 8 b), block 576 (9 waves = 9 p).
// ---------------------------------------------------------------------------
__global__ __launch_bounds__(576) void attn_softmax_k(
    const u16* __restrict__ fgb, const float* __restrict__ aw,
    const float* __restrict__ ab, float* __restrict__ A)
{
    const int lt = blockIdx.x, h = blockIdx.y, b = blockIdx.z;
    const int tid = threadIdx.x, lane = tid & 63;
    const int p = __builtin_amdgcn_readfirstlane(tid >> 6);   // wave-uniform
    const int l = lt * 64 + lane;
    const int row0 = (h * 9 + p) * 9;

    const uint4* fp4 = (const uint4*)&fgb[((size_t)b * LPIX + l) * 128];

    float acc[9];
#pragma unroll
    for (int qq = 0; qq < 9; ++qq) acc[qq] = 0.f;

    for (int cc = 0; cc < 128; cc += 32) {
        float vf[32];
#pragma unroll
        for (int i4 = 0; i4 < 4; ++i4) {
            uint4 uu = fp4[(cc >> 3) + i4];
            vf[i4 * 8 + 0] = __uint_as_float(uu.x << 16);
            vf[i4 * 8 + 1] = __uint_as_float(uu.x & 0xffff0000u);
            vf[i4 * 8 + 2] = __uint_as_float(uu.y << 16);
            vf[i4 * 8 + 3] = __uint_as_float(uu.y & 0xffff0000u);
            vf[i4 * 8 + 4] = __uint_as_float(uu.z << 16);
            vf[i4 * 8 + 5] = __uint_as_float(uu.z & 0xffff0000u);
            vf[i4 * 8 + 6] = __uint_as_float(uu.w << 16);
            vf[i4 * 8 + 7] = __uint_as_float(uu.w & 0xffff0000u);
        }
#pragma unroll
        for (int qq = 0; qq < 9; ++qq) {
            const float* wr = &aw[(size_t)(row0 + qq) * 128 + cc];   // wave-uniform -> s_load
            float s = 0.f;
#pragma unroll
            for (int i = 0; i < 32; ++i) s = fmaf(vf[i], wr[i], s);
            acc[qq] += s;
        }
    }

    float lg[9], m = -1e30f;
#pragma unroll
    for (int qq = 0; qq < 9; ++qq) {
        lg[qq] = (acc[qq] + ab[row0 + qq]) * kScale;
        m = fmaxf(m, lg[qq]);
    }
    float s = 0.f;
#pragma unroll
    for (int qq = 0; qq < 9; ++qq) { lg[qq] = __expf(lg[qq] - m); s += lg[qq]; }
    float inv = 1.f / s;
    float* Ab = &A[(((size_t)(b * 4 + h) * 9 + p) * 9) * LPIX + l];
#pragma unroll
    for (int qq = 0; qq < 9; ++qq) Ab[(size_t)qq * LPIX] = lg[qq] * inv;
}

// ---------------------------------------------------------------------------
// fused einsum + fold (5x5 stencil collapse). v: NHWC bf16; out: NHWC bf16.
// grid (288 tiles of 8x4, 8 b), block 128 = 4 heads x (4y x 8x).
// ---------------------------------------------------------------------------
__global__ __launch_bounds__(128) void attn_fold(
    const float* __restrict__ A, const u16* __restrict__ v,
    u16* __restrict__ out)
{
    const int tile = blockIdx.x;
    const int b    = blockIdx.y;
    const int y0   = (tile / 12) * 4;
    const int x0   = (tile % 12) * 8;
    const int tid  = threadIdx.x;
    const int h    = tid >> 5;
    const int py   = (tid >> 3) & 3;
    const int px   = tid & 7;

    __shared__ float sV[96 * 132];   // [spatial 8x12][c pitch 132] fp32

    for (int i = tid; i < 1536; i += 128) {   // (s 96, c8 16)
        int c8 = i & 15, s = i >> 4;
        int sy = s / 12, sx = s - sy * 12;
        int gy = y0 - 2 + sy, gx = x0 - 2 + sx;
        float4 lo = make_float4(0.f, 0.f, 0.f, 0.f);
        float4 hi = make_float4(0.f, 0.f, 0.f, 0.f);
        if (gy >= 0 && gy < HW && gx >= 0 && gx < HW) {
            const uint4 uu = *(const uint4*)&v[(((size_t)b * HW + gy) * HW + gx) * 128 + c8 * 8];
            lo.x = __uint_as_float(uu.x << 16); lo.y = __uint_as_float(uu.x & 0xffff0000u);
            lo.z = __uint_as_float(uu.y << 16); lo.w = __uint_as_float(uu.y & 0xffff0000u);
            hi.x = __uint_as_float(uu.z << 16); hi.y = __uint_as_float(uu.z & 0xffff0000u);
            hi.z = __uint_as_float(uu.w << 16); hi.w = __uint_as_float(uu.w & 0xffff0000u);
        }
        *(float4*)&sV[s * 132 + c8 * 8]     = lo;
        *(float4*)&sV[s * 132 + c8 * 8 + 4] = hi;
    }
    __syncthreads();

    const int y = y0 + py, x = x0 + px;

    float S[25];
#pragma unroll
    for (int i = 0; i < 25; ++i) S[i] = 0.f;

    const float* Ab = A + ((size_t)(b * 4 + h) * 81) * (size_t)LPIX;
#pragma unroll
    for (int ki = 0; ki < 3; ++ki) {
        int ly = y + 1 - ki;
        bool vy = (ly >= 0 && ly < HW);
#pragma unroll
        for (int kj = 0; kj < 3; ++kj) {
            int lx2 = x + 1 - kj;
            if (vy && lx2 >= 0 && lx2 < HW) {
                const float* Ap = Ab + (size_t)(ki * 3 + kj) * 9 * (size_t)LPIX + ly * HW + lx2;
#pragma unroll
                for (int qq = 0; qq < 9; ++qq) {
                    int qi = qq / 3, qj = qq - qi * 3;
                    S[(qi - ki + 2) * 5 + (qj - kj + 2)] += Ap[(size_t)qq * LPIX];
                }
            }
        }
    }

    float4 acc[8];
#pragma unroll
    for (int k = 0; k < 8; ++k) acc[k] = make_float4(0.f, 0.f, 0.f, 0.f);

#pragma unroll
    for (int oy = 0; oy < 5; ++oy) {
#pragma unroll
        for (int ox = 0; ox < 5; ++ox) {
            float sc = S[oy * 5 + ox];
            const float4* vr = (const float4*)&sV[((py + oy) * 12 + px + ox) * 132 + h * 32];
#pragma unroll
            for (int k = 0; k < 8; ++k) {
                float4 vv = vr[k];
                acc[k].x = fmaf(sc, vv.x, acc[k].x);
                acc[k].y = fmaf(sc, vv.y, acc[k].y);
                acc[k].z = fmaf(sc, vv.z, acc[k].z);
                acc[k].w = fmaf(sc, vv.w, acc[k].w);
            }
        }
    }

    u16* ob = &out[(((size_t)b * HW + y) * HW + x) * 128 + h * 32];
#pragma unroll
    for (int gidx = 0; gidx < 4; ++gidx) {
        union { short8 v8; u16 u[8]; } pk;
        pk.u[0] = f2bf(acc[2 * gidx].x);     pk.u[1] = f2bf(acc[2 * gidx].y);
        pk.u[2] = f2bf(acc[2 * gidx].z);     pk.u[3] = f2bf(acc[2 * gidx].w);
        pk.u[4] = f2bf(acc[2 * gidx + 1].x); pk.u[5] = f2bf(acc[2 * gidx + 1].y);
        pk.u[6] = f2bf(acc[2 * gidx + 1].z); pk.u[7] = f2bf(acc[2 * gidx + 1].w);
        *(short8*)&ob[gidx * 8] = pk.v8;
    }
}

// ---------------------------------------------------------------------------
extern "C" void kernel_launch(void* const* d_in, const int* in_sizes, int n_in,
                              void* d_out, int out_size, void* d_ws, size_t ws_size,
                              hipStream_t stream)
{
    const float* x    = (const float*)d_in[0];
    const float* fg   = (const float*)d_in[1];
    const float* c1w  = (const float*)d_in[2];
    const float* bn1g = (const float*)d_in[3];
    const float* bn1b = (const float*)d_in[4];
    const float* c2w  = (const float*)d_in[5];
    const float* bn2g = (const float*)d_in[6];
    const float* bn2b = (const float*)d_in[7];
    const float* vw   = (const float*)d_in[8];
    const float* vb   = (const float*)d_in[9];
    const float* aw   = (const float*)d_in[10];
    const float* abv  = (const float*)d_in[11];
    const float* pw   = (const float*)d_in[12];
    const float* pb   = (const float*)d_in[13];
    const float* c3w  = (const float*)d_in[14];
    const float* bn3g = (const float*)d_in[15];
    const float* bn3b = (const float*)d_in[16];
    const float* c4w  = (const float*)d_in[17];
    const float* bn4g = (const float*)d_in[18];
    const float* bn4b = (const float*)d_in[19];

    char* wsp = (char*)d_ws;
    size_t off = 0;
    auto carve = [&](size_t bytes) {
        void* pp = wsp + off;
        off += (bytes + 255) & ~(size_t)255;
        return pp;
    };
    u16*   xb   = (u16*)carve((size_t)8 * LPIX * 64 * 2);     // x NHWC bf16
    u16*   fgb  = (u16*)carve((size_t)8 * LPIX * 128 * 2);    // fg NHWC bf16
    u16*   actA = (u16*)carve((size_t)8 * LPIX * 128 * 2);
    u16*   actB = (u16*)carve((size_t)8 * LPIX * 128 * 2);
    float* Abuf = (float*)carve((size_t)8 * 4 * 81 * LPIX * 4);
    u16*   w1p  = (u16*)carve((size_t)9 * 2 * 128 * 32 * 2);
    u16*   w2p  = (u16*)carve((size_t)9 * 4 * 128 * 32 * 2);
    u16*   w3p  = (u16*)carve((size_t)9 * 4 * 128 * 32 * 2);
    u16*   w4p  = (u16*)carve((size_t)9 * 4 * 128 * 32 * 2);
    u16*   vwp  = (u16*)carve((size_t)128 * 128 * 2);
    u16*   pwp  = (u16*)carve((size_t)128 * 128 * 2);

    // --- pre-casts ---
    cast_nchw_nhwc<64><<<dim3(HW, 8), 256, 0, stream>>>(x, xb);
    cast_nchw_nhwc<128><<<dim3(HW, 8), 256, 0, stream>>>(fg, fgb);
    cast_conv_w<<<(9 * 64 * 128 + 255) / 256, 256, 0, stream>>>(c1w, w1p, 64);
    cast_conv_w<<<(9 * 128 * 128 + 255) / 256, 256, 0, stream>>>(c2w, w2p, 128);
    cast_conv_w<<<(9 * 128 * 128 + 255) / 256, 256, 0, stream>>>(c3w, w3p, 128);
    cast_conv_w<<<(9 * 128 * 128 + 255) / 256, 256, 0, stream>>>(c4w, w4p, 128);
    cast_mat<<<(16384 + 255) / 256, 256, 0, stream>>>(vw, vwp, 16384);
    cast_mat<<<(16384 + 255) / 256, 256, 0, stream>>>(pw, pwp, 16384);

    // --- pipeline ---
    conv_mfma<64, false><<<dim3(HW, 8), 256, 0, stream>>>(xb, w1p, bn1g, bn1b, actA);
    conv_mfma<128, false><<<dim3(HW, 8), 256, 0, stream>>>(actA, w2p, bn2g, bn2b, actB);
    linear_mfma<<<1152, 256, 0, stream>>>(actB, vwp, vb, actA);                 // v
    attn_softmax_k<<<dim3(144, 4, 8), 576, 0, stream>>>(fgb, aw, abv, Abuf);
    attn_fold<<<dim3(288, 8), 128, 0, stream>>>(Abuf, actA, actB);              // folded
    linear_mfma<<<1152, 256, 0, stream>>>(actB, pwp, pb, actA);                 // p
    conv_mfma<128, false><<<dim3(HW, 8), 256, 0, stream>>>(actA, w3p, bn3g, bn3b, actB);
    conv_mfma<128, true><<<dim3(HW, 8), 256, 0, stream>>>(actB, w4p, bn4g, bn4b, d_out);
}

// Round 4
// 559.216 us; speedup vs baseline: 5.5854x; 1.2570x over previous
//
#include <hip/hip_runtime.h>
#include <math.h>

typedef __attribute__((ext_vector_type(8))) short short8;
typedef __attribute__((ext_vector_type(4))) float f32x4;
typedef unsigned short u16;
typedef unsigned int u32;

#define HW   96
#define LPIX 9216
static constexpr float kScale = 0.17677669529663687f;  // 1/sqrt(32)

__device__ inline u16 f2bf(float f) {
    u32 x = __float_as_uint(f);
    return (u16)((x + 0x7fffu + ((x >> 16) & 1u)) >> 16);   // RNE
}
__device__ inline float bf2f(u16 v) { return __uint_as_float((u32)v << 16); }

// ---------------------------------------------------------------------------
// NCHW fp32 -> NHWC bf16 transpose-cast. grid (96 y, 8 b), block 256.
// ---------------------------------------------------------------------------
template <int C>
__global__ __launch_bounds__(256) void cast_nchw_nhwc(
    const float* __restrict__ in, u16* __restrict__ out)
{
    const int y = blockIdx.x, b = blockIdx.y, tid = threadIdx.x;
    __shared__ float sT[HW * C];
    for (int i = tid; i < HW * C; i += 256) {
        int c = i / HW, xx = i - c * HW;
        sT[xx * C + c] = in[(((size_t)b * C + c) * HW + y) * HW + xx];
    }
    __syncthreads();
    for (int i = tid; i < HW * (C / 8); i += 256) {
        int c8 = i % (C / 8), xx = i / (C / 8);
        union { short8 v8; u16 u[8]; } pk;
#pragma unroll
        for (int j = 0; j < 8; ++j) pk.u[j] = f2bf(sT[xx * C + c8 * 8 + j]);
        *(short8*)&out[(((size_t)b * HW + y) * HW + xx) * C + c8 * 8] = pk.v8;
    }
}

// ---------------------------------------------------------------------------
// conv weights [co 128][ci CIN][3][3] fp32 -> [f 9][ci/32][co 128][32] bf16
// ---------------------------------------------------------------------------
__global__ void cast_conv_w(const float* __restrict__ w, u16* __restrict__ wp, int CIN)
{
    int n = 9 * CIN * 128;
    int i = blockIdx.x * 256 + threadIdx.x;
    if (i >= n) return;
    int cil = i & 31; int t = i >> 5; int co = t & 127; int t2 = t >> 7;
    int nc5 = CIN >> 5;
    int c5 = t2 % nc5; int f = t2 / nc5;
    int ci = c5 * 32 + cil;
    wp[i] = f2bf(w[(size_t)(co * CIN + ci) * 9 + f]);
}

// dense matrix fp32 -> bf16 (same layout)
__global__ void cast_mat(const float* __restrict__ in, u16* __restrict__ out, int n)
{
    int i = blockIdx.x * 256 + threadIdx.x;
    if (i < n) out[i] = f2bf(in[i]);
}

// ---------------------------------------------------------------------------
// conv3x3 + BN + ReLU via MFMA implicit GEMM.
// in: NHWC bf16 [b][y][x][CIN]; wp: [9][CIN/32][128][32] bf16.
// out: OUT_F32 ? NCHW fp32 : NHWC bf16.
// grid (96 y, 8 b), block 256 (4 waves, 2x2 wave grid: M=64 x N=48 per wave).
// ---------------------------------------------------------------------------
template <int CIN, bool OUT_F32>
__global__ __launch_bounds__(256) void conv_mfma(
    const u16* __restrict__ in, const u16* __restrict__ wp,
    const float* __restrict__ g, const float* __restrict__ be, void* outv)
{
    constexpr int NC5 = CIN / 32;
    const int y0 = blockIdx.x, b = blockIdx.y;
    const int tid = threadIdx.x, lane = tid & 63, wv = tid >> 6;
    const int wm = wv >> 1, wn = wv & 1;
    const int lx = lane & 15, q = lane >> 4;

    __shared__ char smem[3 * 98 * 40 * 2 + 3 * 128 * 40 * 2];   // 54,240 B
    u16* sIn = (u16*)smem;                       // [ki 3][col 98][ci 32 pitch 40]
    u16* sW  = (u16*)(smem + 3 * 98 * 40 * 2);   // [kj 3][co 128][ci 32 pitch 40]
    float* sT = (float*)smem;                    // epilogue reuse [96 px][65]

    f32x4 acc[4][3];
#pragma unroll
    for (int mt = 0; mt < 4; ++mt)
#pragma unroll
        for (int nt = 0; nt < 3; ++nt) acc[mt][nt] = (f32x4){0.f, 0.f, 0.f, 0.f};

    for (int c5 = 0; c5 < NC5; ++c5) {
        for (int ki = 0; ki < 3; ++ki) {
            __syncthreads();   // previous readers done before overwriting LDS
            if (ki == 0) {
                // stage input chunk: 3 rows x 98 cols x 32 ci
                for (int i = tid; i < 1176; i += 256) {
                    int ci8 = i & 3, t = i >> 2, col = t % 98, kr = t / 98;
                    int gy = y0 - 1 + kr, gx = col - 1;
                    short8 v = {0, 0, 0, 0, 0, 0, 0, 0};
                    if (gy >= 0 && gy < HW && gx >= 0 && gx < HW)
                        v = *(const short8*)&in[(((size_t)b * HW + gy) * HW + gx) * CIN
                                                + c5 * 32 + ci8 * 8];
                    *(short8*)&sIn[(kr * 98 + col) * 40 + ci8 * 8] = v;
                }
            }
            // stage weights for 3 kj offsets of this ki
            for (int i = tid; i < 1536; i += 256) {
                int ci8 = i & 3, t = i >> 2, co = t & 127, kj = t >> 7;
                short8 v = *(const short8*)&wp[(size_t)((((ki * 3 + kj) * NC5 + c5) * 128 + co) * 32
                                                         + ci8 * 8)];
                *(short8*)&sW[(kj * 128 + co) * 40 + ci8 * 8] = v;
            }
            __syncthreads();
#pragma unroll
            for (int kj = 0; kj < 3; ++kj) {
                short8 af[4], bfr[3];
#pragma unroll
                for (int mt = 0; mt < 4; ++mt)
                    af[mt] = *(const short8*)&sW[(kj * 128 + wm * 64 + mt * 16 + lx) * 40 + q * 8];
#pragma unroll
                for (int nt = 0; nt < 3; ++nt) {
                    int col = wn * 48 + nt * 16 + lx + kj;   // input x = px + kj - 1
                    bfr[nt] = *(const short8*)&sIn[(ki * 98 + col) * 40 + q * 8];
                }
#pragma unroll
                for (int mt = 0; mt < 4; ++mt)
#pragma unroll
                    for (int nt = 0; nt < 3; ++nt)
                        acc[mt][nt] = __builtin_amdgcn_mfma_f32_16x16x32_bf16(
                            af[mt], bfr[nt], acc[mt][nt], 0, 0, 0);
            }
        }
    }

    const float rs = rsqrtf(1.f + 1e-5f);
    if (OUT_F32) {
        // direct NCHW fp32 store: C-layout cols (px) are lane-consecutive
        float* out = (float*)outv;
#pragma unroll
        for (int mt = 0; mt < 4; ++mt) {
#pragma unroll
            for (int reg = 0; reg < 4; ++reg) {
                int co = wm * 64 + mt * 16 + q * 4 + reg;
                float sc = g[co] * rs, bb = be[co];
#pragma unroll
                for (int nt = 0; nt < 3; ++nt) {
                    int px = wn * 48 + nt * 16 + lx;
                    out[(((size_t)b * 128 + co) * HW + y0) * HW + px] =
                        fmaxf(fmaf(acc[mt][nt][reg], sc, bb), 0.f);
                }
            }
        }
    } else {
        // LDS transpose epilogue -> NHWC bf16 contiguous-channel stores
        u16* out = (u16*)outv;
        for (int mh = 0; mh < 2; ++mh) {
            __syncthreads();
            if (wm == mh) {
#pragma unroll
                for (int mt = 0; mt < 4; ++mt)
#pragma unroll
                    for (int nt = 0; nt < 3; ++nt)
#pragma unroll
                        for (int reg = 0; reg < 4; ++reg)
                            sT[(wn * 48 + nt * 16 + lx) * 65 + mt * 16 + q * 4 + reg] =
                                acc[mt][nt][reg];
            }
            __syncthreads();
            for (int i = tid; i < 768; i += 256) {
                int cog = i & 7, px = i >> 3;
                union { short8 v8; u16 u[8]; } pk;
#pragma unroll
                for (int j = 0; j < 8; ++j) {
                    int co = mh * 64 + cog * 8 + j;
                    pk.u[j] = f2bf(fmaxf(fmaf(sT[px * 65 + cog * 8 + j], g[co] * rs, be[co]), 0.f));
                }
                *(short8*)&out[(((size_t)b * HW + y0) * HW + px) * 128 + mh * 64 + cog * 8] = pk.v8;
            }
        }
    }
}

// ---------------------------------------------------------------------------
// 128->128 linear + bias via MFMA. in/out NHWC-flat bf16 [b*L][128].
// grid 1152 (64 px per block), block 256 (2x2 waves: M=64 x N=32).
// ---------------------------------------------------------------------------
__global__ __launch_bounds__(256) void linear_mfma(
    const u16* __restrict__ in, const u16* __restrict__ wp,
    const float* __restrict__ bias, u16* __restrict__ out)
{
    const int l0 = blockIdx.x * 64;
    const int tid = threadIdx.x, lane = tid & 63, wv = tid >> 6;
    const int wm = wv >> 1, wn = wv & 1;
    const int lx = lane & 15, q = lane >> 4;

    __shared__ char smem[4 * 64 * 40 * 2 + 4 * 128 * 40 * 2];   // 61,440 B
    u16* sX = (u16*)smem;                        // [c4][px 64][32 pitch 40]
    u16* sW = (u16*)(smem + 4 * 64 * 40 * 2);    // [c4][co 128][32 pitch 40]
    float* sT = (float*)smem;                    // epilogue [64][65]

    for (int i = tid; i < 1024; i += 256) {
        int k8 = i & 15, px = i >> 4;
        short8 v = *(const short8*)&in[((size_t)(l0 + px)) * 128 + k8 * 8];
        *(short8*)&sX[((k8 >> 2) * 64 + px) * 40 + (k8 & 3) * 8] = v;
    }
    for (int i = tid; i < 2048; i += 256) {
        int k8 = i & 15, co = i >> 4;
        short8 v = *(const short8*)&wp[(size_t)co * 128 + k8 * 8];
        *(short8*)&sW[((k8 >> 2) * 128 + co) * 40 + (k8 & 3) * 8] = v;
    }
    __syncthreads();

    f32x4 acc[4][2];
#pragma unroll
    for (int mt = 0; mt < 4; ++mt)
#pragma unroll
        for (int nt = 0; nt < 2; ++nt) acc[mt][nt] = (f32x4){0.f, 0.f, 0.f, 0.f};

#pragma unroll
    for (int c4 = 0; c4 < 4; ++c4) {
        short8 af[4], bfr[2];
#pragma unroll
        for (int mt = 0; mt < 4; ++mt)
            af[mt] = *(const short8*)&sW[(c4 * 128 + wm * 64 + mt * 16 + lx) * 40 + q * 8];
#pragma unroll
        for (int nt = 0; nt < 2; ++nt)
            bfr[nt] = *(const short8*)&sX[(c4 * 64 + wn * 32 + nt * 16 + lx) * 40 + q * 8];
#pragma unroll
        for (int mt = 0; mt < 4; ++mt)
#pragma unroll
            for (int nt = 0; nt < 2; ++nt)
                acc[mt][nt] = __builtin_amdgcn_mfma_f32_16x16x32_bf16(
                    af[mt], bfr[nt], acc[mt][nt], 0, 0, 0);
    }

    for (int mh = 0; mh < 2; ++mh) {
        __syncthreads();
        if (wm == mh) {
#pragma unroll
            for (int mt = 0; mt < 4; ++mt)
#pragma unroll
                for (int nt = 0; nt < 2; ++nt)
#pragma unroll
                    for (int reg = 0; reg < 4; ++reg)
                        sT[(wn * 32 + nt * 16 + lx) * 65 + mt * 16 + q * 4 + reg] =
                            acc[mt][nt][reg];
        }
        __syncthreads();
        for (int i = tid; i < 512; i += 256) {
            int cog = i & 7, px = i >> 3;
            union { short8 v8; u16 u[8]; } pk;
#pragma unroll
            for (int j = 0; j < 8; ++j) {
                int co = mh * 64 + cog * 8 + j;
                pk.u[j] = f2bf(sT[px * 65 + cog * 8 + j] + bias[co]);
            }
            *(short8*)&out[((size_t)(l0 + px)) * 128 + mh * 64 + cog * 8] = pk.v8;
        }
    }
}

// ---------------------------------------------------------------------------
// attn logits GEMM (MFMA) + bias + scale + softmax over q(9).
// fgb: NHWC bf16 [b][l][128]; awb: bf16 [324][128]; A out: bf16 [b][h][p][q][L].
// grid (144 l-tiles of 64 px, 4 h, 8 b), block 256 (4 waves).
// Wave wv owns px-tile [wv*16, wv*16+16) x all 96 weight-row cols (81 used).
// ---------------------------------------------------------------------------
__global__ __launch_bounds__(256) void attn_mfma(
    const u16* __restrict__ fgb, const u16* __restrict__ awb,
    const float* __restrict__ ab, u16* __restrict__ A)
{
    const int lt = blockIdx.x, h = blockIdx.y, b = blockIdx.z;
    const int l0 = lt * 64;
    const int tid = threadIdx.x, lane = tid & 63, wv = tid >> 6;
    const int lx = lane & 15, q = lane >> 4;

    __shared__ char smem[4 * 64 * 40 * 2 + 4 * 96 * 40 * 2];   // 51,200 B
    u16* sX = (u16*)smem;                        // [c4][px 64][32 pitch 40]
    u16* sW = (u16*)(smem + 4 * 64 * 40 * 2);    // [c4][row 96][32 pitch 40]
    float* sL = (float*)smem;                    // epilogue logits [px 64][pitch 97]

    for (int i = tid; i < 1024; i += 256) {
        int k8 = i & 15, px = i >> 4;
        short8 v = *(const short8*)&fgb[((size_t)b * LPIX + l0 + px) * 128 + k8 * 8];
        *(short8*)&sX[((k8 >> 2) * 64 + px) * 40 + (k8 & 3) * 8] = v;
    }
    for (int i = tid; i < 1536; i += 256) {
        int k8 = i & 15, rr = i >> 4;           // rr 0..95, rows 81..95 zero-pad
        short8 v = {0, 0, 0, 0, 0, 0, 0, 0};
        if (rr < 81)
            v = *(const short8*)&awb[(size_t)(h * 81 + rr) * 128 + k8 * 8];
        *(short8*)&sW[((k8 >> 2) * 96 + rr) * 40 + (k8 & 3) * 8] = v;
    }
    __syncthreads();

    f32x4 acc[6];
#pragma unroll
    for (int j = 0; j < 6; ++j) acc[j] = (f32x4){0.f, 0.f, 0.f, 0.f};

#pragma unroll
    for (int c4 = 0; c4 < 4; ++c4) {
        // A-operand: this wave's 16 pixels (m = px), B-operand: weight rows (n)
        short8 af = *(const short8*)&sX[(c4 * 64 + wv * 16 + lx) * 40 + q * 8];
#pragma unroll
        for (int j = 0; j < 6; ++j) {
            short8 bfr = *(const short8*)&sW[(c4 * 96 + j * 16 + lx) * 40 + q * 8];
            acc[j] = __builtin_amdgcn_mfma_f32_16x16x32_bf16(af, bfr, acc[j], 0, 0, 0);
        }
    }

    __syncthreads();   // done reading sX/sW; reuse as sL
    // C layout: row(px within tile) = q*4+reg, col(weight row) = j*16+lx
#pragma unroll
    for (int j = 0; j < 6; ++j)
#pragma unroll
        for (int reg = 0; reg < 4; ++reg)
            sL[(wv * 16 + q * 4 + reg) * 97 + j * 16 + lx] = acc[j][reg];
    __syncthreads();

    // softmax over q for each (p, px): 9*64 = 576 tasks
    for (int t = tid; t < 576; t += 256) {
        int px = t & 63, p = t >> 6;
        const int rbase = h * 81 + p * 9;
        float lg[9], m = -1e30f;
#pragma unroll
        for (int qq = 0; qq < 9; ++qq) {
            lg[qq] = (sL[px * 97 + p * 9 + qq] + ab[rbase + qq]) * kScale;
            m = fmaxf(m, lg[qq]);
        }
        float s = 0.f;
#pragma unroll
        for (int qq = 0; qq < 9; ++qq) { lg[qq] = __expf(lg[qq] - m); s += lg[qq]; }
        float inv = 1.f / s;
        u16* Ab = &A[(((size_t)(b * 4 + h) * 9 + p) * 9) * LPIX + l0 + px];
#pragma unroll
        for (int qq = 0; qq < 9; ++qq) Ab[(size_t)qq * LPIX] = f2bf(lg[qq] * inv);
    }
}

// ---------------------------------------------------------------------------
// fused einsum + fold (5x5 stencil collapse). A: bf16; v: NHWC bf16; out NHWC bf16.
// grid (288 tiles of 8x4, 8 b), block 128 = 4 heads x (4y x 8x).
// ---------------------------------------------------------------------------
__global__ __launch_bounds__(128) void attn_fold(
    const u16* __restrict__ A, const u16* __restrict__ v,
    u16* __restrict__ out)
{
    const int tile = blockIdx.x;
    const int b    = blockIdx.y;
    const int y0   = (tile / 12) * 4;
    const int x0   = (tile % 12) * 8;
    const int tid  = threadIdx.x;
    const int h    = tid >> 5;
    const int py   = (tid >> 3) & 3;
    const int px   = tid & 7;

    __shared__ float sV[96 * 132];   // [spatial 8x12][c pitch 132] fp32

    for (int i = tid; i < 1536; i += 128) {   // (s 96, c8 16)
        int c8 = i & 15, s = i >> 4;
        int sy = s / 12, sx = s - sy * 12;
        int gy = y0 - 2 + sy, gx = x0 - 2 + sx;
        float4 lo = make_float4(0.f, 0.f, 0.f, 0.f);
        float4 hi = make_float4(0.f, 0.f, 0.f, 0.f);
        if (gy >= 0 && gy < HW && gx >= 0 && gx < HW) {
            const uint4 uu = *(const uint4*)&v[(((size_t)b * HW + gy) * HW + gx) * 128 + c8 * 8];
            lo.x = __uint_as_float(uu.x << 16); lo.y = __uint_as_float(uu.x & 0xffff0000u);
            lo.z = __uint_as_float(uu.y << 16); lo.w = __uint_as_float(uu.y & 0xffff0000u);
            hi.x = __uint_as_float(uu.z << 16); hi.y = __uint_as_float(uu.z & 0xffff0000u);
            hi.z = __uint_as_float(uu.w << 16); hi.w = __uint_as_float(uu.w & 0xffff0000u);
        }
        *(float4*)&sV[s * 132 + c8 * 8]     = lo;
        *(float4*)&sV[s * 132 + c8 * 8 + 4] = hi;
    }
    __syncthreads();

    const int y = y0 + py, x = x0 + px;

    float S[25];
#pragma unroll
    for (int i = 0; i < 25; ++i) S[i] = 0.f;

    const u16* Ab = A + ((size_t)(b * 4 + h) * 81) * (size_t)LPIX;
#pragma unroll
    for (int ki = 0; ki < 3; ++ki) {
        int ly = y + 1 - ki;
        bool vy = (ly >= 0 && ly < HW);
#pragma unroll
        for (int kj = 0; kj < 3; ++kj) {
            int lx2 = x + 1 - kj;
            if (vy && lx2 >= 0 && lx2 < HW) {
                const u16* Ap = Ab + (size_t)(ki * 3 + kj) * 9 * (size_t)LPIX + ly * HW + lx2;
#pragma unroll
                for (int qq = 0; qq < 9; ++qq) {
                    int qi = qq / 3, qj = qq - qi * 3;
                    S[(qi - ki + 2) * 5 + (qj - kj + 2)] += bf2f(Ap[(size_t)qq * LPIX]);
                }
            }
        }
    }

    float4 acc[8];
#pragma unroll
    for (int k = 0; k < 8; ++k) acc[k] = make_float4(0.f, 0.f, 0.f, 0.f);

#pragma unroll
    for (int oy = 0; oy < 5; ++oy) {
#pragma unroll
        for (int ox = 0; ox < 5; ++ox) {
            float sc = S[oy * 5 + ox];
            const float4* vr = (const float4*)&sV[((py + oy) * 12 + px + ox) * 132 + h * 32];
#pragma unroll
            for (int k = 0; k < 8; ++k) {
                float4 vv = vr[k];
                acc[k].x = fmaf(sc, vv.x, acc[k].x);
                acc[k].y = fmaf(sc, vv.y, acc[k].y);
                acc[k].z = fmaf(sc, vv.z, acc[k].z);
                acc[k].w = fmaf(sc, vv.w, acc[k].w);
            }
        }
    }

    u16* ob = &out[(((size_t)b * HW + y) * HW + x) * 128 + h * 32];
#pragma unroll
    for (int gidx = 0; gidx < 4; ++gidx) {
        union { short8 v8; u16 u[8]; } pk;
        pk.u[0] = f2bf(acc[2 * gidx].x);     pk.u[1] = f2bf(acc[2 * gidx].y);
        pk.u[2] = f2bf(acc[2 * gidx].z);     pk.u[3] = f2bf(acc[2 * gidx].w);
        pk.u[4] = f2bf(acc[2 * gidx + 1].x); pk.u[5] = f2bf(acc[2 * gidx + 1].y);
        pk.u[6] = f2bf(acc[2 * gidx + 1].z); pk.u[7] = f2bf(acc[2 * gidx + 1].w);
        *(short8*)&ob[gidx * 8] = pk.v8;
    }
}

// ---------------------------------------------------------------------------
extern "C" void kernel_launch(void* const* d_in, const int* in_sizes, int n_in,
                              void* d_out, int out_size, void* d_ws, size_t ws_size,
                              hipStream_t stream)
{
    const float* x    = (const float*)d_in[0];
    const float* fg   = (const float*)d_in[1];
    const float* c1w  = (const float*)d_in[2];
    const float* bn1g = (const float*)d_in[3];
    const float* bn1b = (const float*)d_in[4];
    const float* c2w  = (const float*)d_in[5];
    const float* bn2g = (const float*)d_in[6];
    const float* bn2b = (const float*)d_in[7];
    const float* vw   = (const float*)d_in[8];
    const float* vb   = (const float*)d_in[9];
    const float* aw   = (const float*)d_in[10];
    const float* abv  = (const float*)d_in[11];
    const float* pw   = (const float*)d_in[12];
    const float* pb   = (const float*)d_in[13];
    const float* c3w  = (const float*)d_in[14];
    const float* bn3g = (const float*)d_in[15];
    const float* bn3b = (const float*)d_in[16];
    const float* c4w  = (const float*)d_in[17];
    const float* bn4g = (const float*)d_in[18];
    const float* bn4b = (const float*)d_in[19];

    char* wsp = (char*)d_ws;
    size_t off = 0;
    auto carve = [&](size_t bytes) {
        void* pp = wsp + off;
        off += (bytes + 255) & ~(size_t)255;
        return pp;
    };
    u16*   xb   = (u16*)carve((size_t)8 * LPIX * 64 * 2);     // x NHWC bf16
    u16*   fgb  = (u16*)carve((size_t)8 * LPIX * 128 * 2);    // fg NHWC bf16
    u16*   actA = (u16*)carve((size_t)8 * LPIX * 128 * 2);
    u16*   actB = (u16*)carve((size_t)8 * LPIX * 128 * 2);
    u16*   Abuf = (u16*)carve((size_t)8 * 324 * LPIX * 2);    // A bf16
    u16*   w1p  = (u16*)carve((size_t)9 * 2 * 128 * 32 * 2);
    u16*   w2p  = (u16*)carve((size_t)9 * 4 * 128 * 32 * 2);
    u16*   w3p  = (u16*)carve((size_t)9 * 4 * 128 * 32 * 2);
    u16*   w4p  = (u16*)carve((size_t)9 * 4 * 128 * 32 * 2);
    u16*   vwp  = (u16*)carve((size_t)128 * 128 * 2);
    u16*   pwp  = (u16*)carve((size_t)128 * 128 * 2);
    u16*   awb  = (u16*)carve((size_t)324 * 128 * 2);

    // --- pre-casts ---
    cast_nchw_nhwc<64><<<dim3(HW, 8), 256, 0, stream>>>(x, xb);
    cast_nchw_nhwc<128><<<dim3(HW, 8), 256, 0, stream>>>(fg, fgb);
    cast_conv_w<<<(9 * 64 * 128 + 255) / 256, 256, 0, stream>>>(c1w, w1p, 64);
    cast_conv_w<<<(9 * 128 * 128 + 255) / 256, 256, 0, stream>>>(c2w, w2p, 128);
    cast_conv_w<<<(9 * 128 * 128 + 255) / 256, 256, 0, stream>>>(c3w, w3p, 128);
    cast_conv_w<<<(9 * 128 * 128 + 255) / 256, 256, 0, stream>>>(c4w, w4p, 128);
    cast_mat<<<(16384 + 255) / 256, 256, 0, stream>>>(vw, vwp, 16384);
    cast_mat<<<(16384 + 255) / 256, 256, 0, stream>>>(pw, pwp, 16384);
    cast_mat<<<(324 * 128 + 255) / 256, 256, 0, stream>>>(aw, awb, 324 * 128);

    // --- pipeline ---
    conv_mfma<64, false><<<dim3(HW, 8), 256, 0, stream>>>(xb, w1p, bn1g, bn1b, actA);
    conv_mfma<128, false><<<dim3(HW, 8), 256, 0, stream>>>(actA, w2p, bn2g, bn2b, actB);
    linear_mfma<<<1152, 256, 0, stream>>>(actB, vwp, vb, actA);                 // v
    attn_mfma<<<dim3(144, 4, 8), 256, 0, stream>>>(fgb, awb, abv, Abuf);
    attn_fold<<<dim3(288, 8), 128, 0, stream>>>(Abuf, actA, actB);              // folded
    linear_mfma<<<1152, 256, 0, stream>>>(actB, pwp, pb, actA);                 // p
    conv_mfma<128, false><<<dim3(HW, 8), 256, 0, stream>>>(actA, w3p, bn3g, bn3b, actB);
    conv_mfma<128, true><<<dim3(HW, 8), 256, 0, stream>>>(actB, w4p, bn4g, bn4b, d_out);
}

// Round 6
// 504.785 us; speedup vs baseline: 6.1877x; 1.1078x over previous
//
#include <hip/hip_runtime.h>
#include <math.h>

typedef __attribute__((ext_vector_type(8))) short short8;
typedef __attribute__((ext_vector_type(4))) float f32x4;
typedef unsigned short u16;
typedef unsigned int u32;

#define HW   96
#define LPIX 9216
static constexpr float kScale = 0.17677669529663687f;  // 1/sqrt(32)

__device__ inline u16 f2bf(float f) {
    u32 x = __float_as_uint(f);
    return (u16)((x + 0x7fffu + ((x >> 16) & 1u)) >> 16);   // RNE
}
__device__ inline float bf2f(u16 v) { return __uint_as_float((u32)v << 16); }

// ---------------------------------------------------------------------------
// NCHW fp32 -> NHWC bf16 transpose-cast. grid (96 y, 8 b), block 256.
// ---------------------------------------------------------------------------
template <int C>
__global__ __launch_bounds__(256) void cast_nchw_nhwc(
    const float* __restrict__ in, u16* __restrict__ out)
{
    const int y = blockIdx.x, b = blockIdx.y, tid = threadIdx.x;
    __shared__ float sT[HW * C];
    for (int i = tid; i < HW * C; i += 256) {
        int c = i / HW, xx = i - c * HW;
        sT[xx * C + c] = in[(((size_t)b * C + c) * HW + y) * HW + xx];
    }
    __syncthreads();
    for (int i = tid; i < HW * (C / 8); i += 256) {
        int c8 = i % (C / 8), xx = i / (C / 8);
        union { short8 v8; u16 u[8]; } pk;
#pragma unroll
        for (int j = 0; j < 8; ++j) pk.u[j] = f2bf(sT[xx * C + c8 * 8 + j]);
        *(short8*)&out[(((size_t)b * HW + y) * HW + xx) * C + c8 * 8] = pk.v8;
    }
}

// ---------------------------------------------------------------------------
// conv weights [co 128][ci CIN][3][3] fp32 -> [f 9][ci/32][co 128][32] bf16
// ---------------------------------------------------------------------------
__global__ void cast_conv_w(const float* __restrict__ w, u16* __restrict__ wp, int CIN)
{
    int n = 9 * CIN * 128;
    int i = blockIdx.x * 256 + threadIdx.x;
    if (i >= n) return;
    int cil = i & 31; int t = i >> 5; int co = t & 127; int t2 = t >> 7;
    int nc5 = CIN >> 5;
    int c5 = t2 % nc5; int f = t2 / nc5;
    int ci = c5 * 32 + cil;
    wp[i] = f2bf(w[(size_t)(co * CIN + ci) * 9 + f]);
}

// dense matrix fp32 -> bf16 (same layout)
__global__ void cast_mat(const float* __restrict__ in, u16* __restrict__ out, int n)
{
    int i = blockIdx.x * 256 + threadIdx.x;
    if (i < n) out[i] = f2bf(in[i]);
}

// ---------------------------------------------------------------------------
// conv3x3 + BN + ReLU as flat GEMM over pixels (implicit im2col).
// M=128 co x N=128 flat pixels per block; K-loop = 9 taps x 64-ci chunks.
// in: NHWC bf16; wp: [9][CIN/32][128][32] bf16.
// out: OUT_F32 ? NCHW fp32 : NHWC bf16.
// grid (72 px-blocks, 8 b), block 256 (2x2 waves, each M=64 x N=64).
// LDS 36,864 B -> 3 blocks/CU with __launch_bounds__(256,3).
// ---------------------------------------------------------------------------
template <int CIN, bool OUT_F32>
__global__ __launch_bounds__(256, 3) void conv_gemm(
    const u16* __restrict__ in, const u16* __restrict__ wp,
    const float* __restrict__ g, const float* __restrict__ be, void* outv)
{
    constexpr int NC6 = CIN / 64;       // 64-ci chunks
    constexpr int NC5 = CIN / 32;
    const int l0 = blockIdx.x * 128;
    const int b  = blockIdx.y;
    const int tid = threadIdx.x, lane = tid & 63, wv = tid >> 6;
    const int wm = wv >> 1, wn = wv & 1;
    const int lx = lane & 15, q = lane >> 4;

    __shared__ char smem[36864];
    u16* sA = (u16*)smem;               // [co 128][ci 64 pitch 72]
    u16* sB = sA + 128 * 72;            // [px 128][ci 64 pitch 72]
    float* sT = (float*)smem;           // epilogue [px 128][co 64 pitch 65] (33,280 B)

    f32x4 acc[4][4];                    // [mt co][nt px]
#pragma unroll
    for (int mt = 0; mt < 4; ++mt)
#pragma unroll
        for (int nt = 0; nt < 4; ++nt) acc[mt][nt] = (f32x4){0.f, 0.f, 0.f, 0.f};

    for (int c6 = 0; c6 < NC6; ++c6) {
        for (int f = 0; f < 9; ++f) {
            const int dy = f / 3 - 1, dx = f % 3 - 1;
            __syncthreads();
            // stage A (weights): 1024 short8, coalesced from wp
            for (int i = tid; i < 1024; i += 256) {
                int ci8 = i & 7, co = i >> 3;
                int c5 = c6 * 2 + (ci8 >> 2);
                short8 v = *(const short8*)&wp[(size_t)(((f * NC5 + c5) * 128 + co) * 32
                                                         + (ci8 & 3) * 8)];
                *(short8*)&sA[co * 72 + ci8 * 8] = v;
            }
            // stage B (shifted input pixels): chunk is always 64 ci ->
            // 8 short8 per pixel x 128 pixels = 1024 tasks (fixed from R5 bug)
            for (int i = tid; i < 1024; i += 256) {
                int ci8 = i & 7, p = i >> 3;
                int l = l0 + p;
                int y = l / 96, x = l - y * 96;
                int yy = y + dy, xx = x + dx;
                short8 v = {0, 0, 0, 0, 0, 0, 0, 0};
                if (yy >= 0 && yy < HW && xx >= 0 && xx < HW)
                    v = *(const short8*)&in[(((size_t)b * HW + yy) * HW + xx) * CIN
                                            + c6 * 64 + ci8 * 8];
                *(short8*)&sB[p * 72 + ci8 * 8] = v;
            }
            __syncthreads();
#pragma unroll
            for (int kk = 0; kk < 2; ++kk) {
                short8 af[4], bfr[4];
#pragma unroll
                for (int mt = 0; mt < 4; ++mt)
                    af[mt] = *(const short8*)&sA[(wm * 64 + mt * 16 + lx) * 72 + kk * 32 + q * 8];
#pragma unroll
                for (int nt = 0; nt < 4; ++nt)
                    bfr[nt] = *(const short8*)&sB[(wn * 64 + nt * 16 + lx) * 72 + kk * 32 + q * 8];
#pragma unroll
                for (int mt = 0; mt < 4; ++mt)
#pragma unroll
                    for (int nt = 0; nt < 4; ++nt)
                        acc[mt][nt] = __builtin_amdgcn_mfma_f32_16x16x32_bf16(
                            af[mt], bfr[nt], acc[mt][nt], 0, 0, 0);
            }
        }
    }

    const float rs = rsqrtf(1.f + 1e-5f);
    if (OUT_F32) {
        // direct NCHW fp32 store: px (cols) are lane-consecutive
        float* out = (float*)outv;
#pragma unroll
        for (int mt = 0; mt < 4; ++mt) {
#pragma unroll
            for (int reg = 0; reg < 4; ++reg) {
                int co = wm * 64 + mt * 16 + q * 4 + reg;
                float sc = g[co] * rs, bb = be[co];
#pragma unroll
                for (int nt = 0; nt < 4; ++nt) {
                    int l = l0 + wn * 64 + nt * 16 + lx;
                    out[((size_t)b * 128 + co) * LPIX + l] =
                        fmaxf(fmaf(acc[mt][nt][reg], sc, bb), 0.f);
                }
            }
        }
    } else {
        // LDS transpose epilogue -> NHWC bf16, two co-halves
        u16* out = (u16*)outv;
        for (int mh = 0; mh < 2; ++mh) {
            __syncthreads();
            if (wm == mh) {
#pragma unroll
                for (int mt = 0; mt < 4; ++mt)
#pragma unroll
                    for (int nt = 0; nt < 4; ++nt)
#pragma unroll
                        for (int reg = 0; reg < 4; ++reg)
                            sT[(wn * 64 + nt * 16 + lx) * 65 + mt * 16 + q * 4 + reg] =
                                acc[mt][nt][reg];
            }
            __syncthreads();
            for (int i = tid; i < 1024; i += 256) {
                int cog = i & 7, px = i >> 3;
                union { short8 v8; u16 u[8]; } pk;
#pragma unroll
                for (int j = 0; j < 8; ++j) {
                    int co = mh * 64 + cog * 8 + j;
                    pk.u[j] = f2bf(fmaxf(fmaf(sT[px * 65 + cog * 8 + j], g[co] * rs, be[co]), 0.f));
                }
                *(short8*)&out[((size_t)b * LPIX + l0 + px) * 128 + mh * 64 + cog * 8] = pk.v8;
            }
        }
    }
}

// ---------------------------------------------------------------------------
// 128->128 linear + bias via MFMA. in/out NHWC-flat bf16 [b*L][128].
// grid 1152 (64 px per block), block 256 (2x2 waves: M=64 x N=32).
// ---------------------------------------------------------------------------
__global__ __launch_bounds__(256) void linear_mfma(
    const u16* __restrict__ in, const u16* __restrict__ wp,
    const float* __restrict__ bias, u16* __restrict__ out)
{
    const int l0 = blockIdx.x * 64;
    const int tid = threadIdx.x, lane = tid & 63, wv = tid >> 6;
    const int wm = wv >> 1, wn = wv & 1;
    const int lx = lane & 15, q = lane >> 4;

    __shared__ char smem[4 * 64 * 40 * 2 + 4 * 128 * 40 * 2];   // 61,440 B
    u16* sX = (u16*)smem;                        // [c4][px 64][32 pitch 40]
    u16* sW = (u16*)(smem + 4 * 64 * 40 * 2);    // [c4][co 128][32 pitch 40]
    float* sT = (float*)smem;                    // epilogue [64][65]

    for (int i = tid; i < 1024; i += 256) {
        int k8 = i & 15, px = i >> 4;
        short8 v = *(const short8*)&in[((size_t)(l0 + px)) * 128 + k8 * 8];
        *(short8*)&sX[((k8 >> 2) * 64 + px) * 40 + (k8 & 3) * 8] = v;
    }
    for (int i = tid; i < 2048; i += 256) {
        int k8 = i & 15, co = i >> 4;
        short8 v = *(const short8*)&wp[(size_t)co * 128 + k8 * 8];
        *(short8*)&sW[((k8 >> 2) * 128 + co) * 40 + (k8 & 3) * 8] = v;
    }
    __syncthreads();

    f32x4 acc[4][2];
#pragma unroll
    for (int mt = 0; mt < 4; ++mt)
#pragma unroll
        for (int nt = 0; nt < 2; ++nt) acc[mt][nt] = (f32x4){0.f, 0.f, 0.f, 0.f};

#pragma unroll
    for (int c4 = 0; c4 < 4; ++c4) {
        short8 af[4], bfr[2];
#pragma unroll
        for (int mt = 0; mt < 4; ++mt)
            af[mt] = *(const short8*)&sW[(c4 * 128 + wm * 64 + mt * 16 + lx) * 40 + q * 8];
#pragma unroll
        for (int nt = 0; nt < 2; ++nt)
            bfr[nt] = *(const short8*)&sX[(c4 * 64 + wn * 32 + nt * 16 + lx) * 40 + q * 8];
#pragma unroll
        for (int mt = 0; mt < 4; ++mt)
#pragma unroll
            for (int nt = 0; nt < 2; ++nt)
                acc[mt][nt] = __builtin_amdgcn_mfma_f32_16x16x32_bf16(
                    af[mt], bfr[nt], acc[mt][nt], 0, 0, 0);
    }

    for (int mh = 0; mh < 2; ++mh) {
        __syncthreads();
        if (wm == mh) {
#pragma unroll
            for (int mt = 0; mt < 4; ++mt)
#pragma unroll
                for (int nt = 0; nt < 2; ++nt)
#pragma unroll
                    for (int reg = 0; reg < 4; ++reg)
                        sT[(wn * 32 + nt * 16 + lx) * 65 + mt * 16 + q * 4 + reg] =
                            acc[mt][nt][reg];
        }
        __syncthreads();
        for (int i = tid; i < 512; i += 256) {
            int cog = i & 7, px = i >> 3;
            union { short8 v8; u16 u[8]; } pk;
#pragma unroll
            for (int j = 0; j < 8; ++j) {
                int co = mh * 64 + cog * 8 + j;
                pk.u[j] = f2bf(sT[px * 65 + cog * 8 + j] + bias[co]);
            }
            *(short8*)&out[((size_t)(l0 + px)) * 128 + mh * 64 + cog * 8] = pk.v8;
        }
    }
}

// ---------------------------------------------------------------------------
// attn logits GEMM (MFMA) + bias + scale + softmax over q(9).
// fgb: NHWC bf16 [b][l][128]; awb: bf16 [324][128]; A out: bf16 [b][h][p][q][L].
// grid (144 l-tiles of 64 px, 4 h, 8 b), block 256 (4 waves).
// ---------------------------------------------------------------------------
__global__ __launch_bounds__(256) void attn_mfma(
    const u16* __restrict__ fgb, const u16* __restrict__ awb,
    const float* __restrict__ ab, u16* __restrict__ A)
{
    const int lt = blockIdx.x, h = blockIdx.y, b = blockIdx.z;
    const int l0 = lt * 64;
    const int tid = threadIdx.x, lane = tid & 63, wv = tid >> 6;
    const int lx = lane & 15, q = lane >> 4;

    __shared__ char smem[4 * 64 * 40 * 2 + 4 * 96 * 40 * 2];   // 51,200 B
    u16* sX = (u16*)smem;                        // [c4][px 64][32 pitch 40]
    u16* sW = (u16*)(smem + 4 * 64 * 40 * 2);    // [c4][row 96][32 pitch 40]
    float* sL = (float*)smem;                    // epilogue logits [px 64][pitch 97]

    for (int i = tid; i < 1024; i += 256) {
        int k8 = i & 15, px = i >> 4;
        short8 v = *(const short8*)&fgb[((size_t)b * LPIX + l0 + px) * 128 + k8 * 8];
        *(short8*)&sX[((k8 >> 2) * 64 + px) * 40 + (k8 & 3) * 8] = v;
    }
    for (int i = tid; i < 1536; i += 256) {
        int k8 = i & 15, rr = i >> 4;           // rr 0..95, rows 81..95 zero-pad
        short8 v = {0, 0, 0, 0, 0, 0, 0, 0};
        if (rr < 81)
            v = *(const short8*)&awb[(size_t)(h * 81 + rr) * 128 + k8 * 8];
        *(short8*)&sW[((k8 >> 2) * 96 + rr) * 40 + (k8 & 3) * 8] = v;
    }
    __syncthreads();

    f32x4 acc[6];
#pragma unroll
    for (int j = 0; j < 6; ++j) acc[j] = (f32x4){0.f, 0.f, 0.f, 0.f};

#pragma unroll
    for (int c4 = 0; c4 < 4; ++c4) {
        short8 af = *(const short8*)&sX[(c4 * 64 + wv * 16 + lx) * 40 + q * 8];
#pragma unroll
        for (int j = 0; j < 6; ++j) {
            short8 bfr = *(const short8*)&sW[(c4 * 96 + j * 16 + lx) * 40 + q * 8];
            acc[j] = __builtin_amdgcn_mfma_f32_16x16x32_bf16(af, bfr, acc[j], 0, 0, 0);
        }
    }

    __syncthreads();   // done reading sX/sW; reuse as sL
#pragma unroll
    for (int j = 0; j < 6; ++j)
#pragma unroll
        for (int reg = 0; reg < 4; ++reg)
            sL[(wv * 16 + q * 4 + reg) * 97 + j * 16 + lx] = acc[j][reg];
    __syncthreads();

    for (int t = tid; t < 576; t += 256) {
        int px = t & 63, p = t >> 6;
        const int rbase = h * 81 + p * 9;
        float lg[9], m = -1e30f;
#pragma unroll
        for (int qq = 0; qq < 9; ++qq) {
            lg[qq] = (sL[px * 97 + p * 9 + qq] + ab[rbase + qq]) * kScale;
            m = fmaxf(m, lg[qq]);
        }
        float s = 0.f;
#pragma unroll
        for (int qq = 0; qq < 9; ++qq) { lg[qq] = __expf(lg[qq] - m); s += lg[qq]; }
        float inv = 1.f / s;
        u16* Ab = &A[(((size_t)(b * 4 + h) * 9 + p) * 9) * LPIX + l0 + px];
#pragma unroll
        for (int qq = 0; qq < 9; ++qq) Ab[(size_t)qq * LPIX] = f2bf(lg[qq] * inv);
    }
}

// ---------------------------------------------------------------------------
// fused einsum + fold (5x5 stencil collapse). A: bf16; v: NHWC bf16; out NHWC bf16.
// grid (288 tiles of 8x4, 8 b), block 128 = 4 heads x (4y x 8x).
// ---------------------------------------------------------------------------
__global__ __launch_bounds__(128) void attn_fold(
    const u16* __restrict__ A, const u16* __restrict__ v,
    u16* __restrict__ out)
{
    const int tile = blockIdx.x;
    const int b    = blockIdx.y;
    const int y0   = (tile / 12) * 4;
    const int x0   = (tile % 12) * 8;
    const int tid  = threadIdx.x;
    const int h    = tid >> 5;
    const int py   = (tid >> 3) & 3;
    const int px   = tid & 7;

    __shared__ float sV[96 * 132];   // [spatial 8x12][c pitch 132] fp32

    for (int i = tid; i < 1536; i += 128) {   // (s 96, c8 16)
        int c8 = i & 15, s = i >> 4;
        int sy = s / 12, sx = s - sy * 12;
        int gy = y0 - 2 + sy, gx = x0 - 2 + sx;
        float4 lo = make_float4(0.f, 0.f, 0.f, 0.f);
        float4 hi = make_float4(0.f, 0.f, 0.f, 0.f);
        if (gy >= 0 && gy < HW && gx >= 0 && gx < HW) {
            const uint4 uu = *(const uint4*)&v[(((size_t)b * HW + gy) * HW + gx) * 128 + c8 * 8];
            lo.x = __uint_as_float(uu.x << 16); lo.y = __uint_as_float(uu.x & 0xffff0000u);
            lo.z = __uint_as_float(uu.y << 16); lo.w = __uint_as_float(uu.y & 0xffff0000u);
            hi.x = __uint_as_float(uu.z << 16); hi.y = __uint_as_float(uu.z & 0xffff0000u);
            hi.z = __uint_as_float(uu.w << 16); hi.w = __uint_as_float(uu.w & 0xffff0000u);
        }
        *(float4*)&sV[s * 132 + c8 * 8]     = lo;
        *(float4*)&sV[s * 132 + c8 * 8 + 4] = hi;
    }
    __syncthreads();

    const int y = y0 + py, x = x0 + px;

    float S[25];
#pragma unroll
    for (int i = 0; i < 25; ++i) S[i] = 0.f;

    const u16* Ab = A + ((size_t)(b * 4 + h) * 81) * (size_t)LPIX;
#pragma unroll
    for (int ki = 0; ki < 3; ++ki) {
        int ly = y + 1 - ki;
        bool vy = (ly >= 0 && ly < HW);
#pragma unroll
        for (int kj = 0; kj < 3; ++kj) {
            int lx2 = x + 1 - kj;
            if (vy && lx2 >= 0 && lx2 < HW) {
                const u16* Ap = Ab + (size_t)(ki * 3 + kj) * 9 * (size_t)LPIX + ly * HW + lx2;
#pragma unroll
                for (int qq = 0; qq < 9; ++qq) {
                    int qi = qq / 3, qj = qq - qi * 3;
                    S[(qi - ki + 2) * 5 + (qj - kj + 2)] += bf2f(Ap[(size_t)qq * LPIX]);
                }
            }
        }
    }

    float4 acc[8];
#pragma unroll
    for (int k = 0; k < 8; ++k) acc[k] = make_float4(0.f, 0.f, 0.f, 0.f);

#pragma unroll
    for (int oy = 0; oy < 5; ++oy) {
#pragma unroll
        for (int ox = 0; ox < 5; ++ox) {
            float sc = S[oy * 5 + ox];
            const float4* vr = (const float4*)&sV[((py + oy) * 12 + px + ox) * 132 + h * 32];
#pragma unroll
            for (int k = 0; k < 8; ++k) {
                float4 vv = vr[k];
                acc[k].x = fmaf(sc, vv.x, acc[k].x);
                acc[k].y = fmaf(sc, vv.y, acc[k].y);
                acc[k].z = fmaf(sc, vv.z, acc[k].z);
                acc[k].w = fmaf(sc, vv.w, acc[k].w);
            }
        }
    }

    u16* ob = &out[(((size_t)b * HW + y) * HW + x) * 128 + h * 32];
#pragma unroll
    for (int gidx = 0; gidx < 4; ++gidx) {
        union { short8 v8; u16 u[8]; } pk;
        pk.u[0] = f2bf(acc[2 * gidx].x);     pk.u[1] = f2bf(acc[2 * gidx].y);
        pk.u[2] = f2bf(acc[2 * gidx].z);     pk.u[3] = f2bf(acc[2 * gidx].w);
        pk.u[4] = f2bf(acc[2 * gidx + 1].x); pk.u[5] = f2bf(acc[2 * gidx + 1].y);
        pk.u[6] = f2bf(acc[2 * gidx + 1].z); pk.u[7] = f2bf(acc[2 * gidx + 1].w);
        *(short8*)&ob[gidx * 8] = pk.v8;
    }
}

// ---------------------------------------------------------------------------
extern "C" void kernel_launch(void* const* d_in, const int* in_sizes, int n_in,
                              void* d_out, int out_size, void* d_ws, size_t ws_size,
                              hipStream_t stream)
{
    const float* x    = (const float*)d_in[0];
    const float* fg   = (const float*)d_in[1];
    const float* c1w  = (const float*)d_in[2];
    const float* bn1g = (const float*)d_in[3];
    const float* bn1b = (const float*)d_in[4];
    const float* c2w  = (const float*)d_in[5];
    const float* bn2g = (const float*)d_in[6];
    const float* bn2b = (const float*)d_in[7];
    const float* vw   = (const float*)d_in[8];
    const float* vb   = (const float*)d_in[9];
    const float* aw   = (const float*)d_in[10];
    const float* abv  = (const float*)d_in[11];
    const float* pw   = (const float*)d_in[12];
    const float* pb   = (const float*)d_in[13];
    const float* c3w  = (const float*)d_in[14];
    const float* bn3g = (const float*)d_in[15];
    const float* bn3b = (const float*)d_in[16];
    const float* c4w  = (const float*)d_in[17];
    const float* bn4g = (const float*)d_in[18];
    const float* bn4b = (const float*)d_in[19];

    char* wsp = (char*)d_ws;
    size_t off = 0;
    auto carve = [&](size_t bytes) {
        void* pp = wsp + off;
        off += (bytes + 255) & ~(size_t)255;
        return pp;
    };
    u16*   xb   = (u16*)carve((size_t)8 * LPIX * 64 * 2);     // x NHWC bf16
    u16*   fgb  = (u16*)carve((size_t)8 * LPIX * 128 * 2);    // fg NHWC bf16
    u16*   actA = (u16*)carve((size_t)8 * LPIX * 128 * 2);
    u16*   actB = (u16*)carve((size_t)8 * LPIX * 128 * 2);
    u16*   Abuf = (u16*)carve((size_t)8 * 324 * LPIX * 2);    // A bf16
    u16*   w1p  = (u16*)carve((size_t)9 * 2 * 128 * 32 * 2);
    u16*   w2p  = (u16*)carve((size_t)9 * 4 * 128 * 32 * 2);
    u16*   w3p  = (u16*)carve((size_t)9 * 4 * 128 * 32 * 2);
    u16*   w4p  = (u16*)carve((size_t)9 * 4 * 128 * 32 * 2);
    u16*   vwp  = (u16*)carve((size_t)128 * 128 * 2);
    u16*   pwp  = (u16*)carve((size_t)128 * 128 * 2);
    u16*   awb  = (u16*)carve((size_t)324 * 128 * 2);

    // --- pre-casts ---
    cast_nchw_nhwc<64><<<dim3(HW, 8), 256, 0, stream>>>(x, xb);
    cast_nchw_nhwc<128><<<dim3(HW, 8), 256, 0, stream>>>(fg, fgb);
    cast_conv_w<<<(9 * 64 * 128 + 255) / 256, 256, 0, stream>>>(c1w, w1p, 64);
    cast_conv_w<<<(9 * 128 * 128 + 255) / 256, 256, 0, stream>>>(c2w, w2p, 128);
    cast_conv_w<<<(9 * 128 * 128 + 255) / 256, 256, 0, stream>>>(c3w, w3p, 128);
    cast_conv_w<<<(9 * 128 * 128 + 255) / 256, 256, 0, stream>>>(c4w, w4p, 128);
    cast_mat<<<(16384 + 255) / 256, 256, 0, stream>>>(vw, vwp, 16384);
    cast_mat<<<(16384 + 255) / 256, 256, 0, stream>>>(pw, pwp, 16384);
    cast_mat<<<(324 * 128 + 255) / 256, 256, 0, stream>>>(aw, awb, 324 * 128);

    // --- pipeline ---
    conv_gemm<64, false><<<dim3(72, 8), 256, 0, stream>>>(xb, w1p, bn1g, bn1b, actA);
    conv_gemm<128, false><<<dim3(72, 8), 256, 0, stream>>>(actA, w2p, bn2g, bn2b, actB);
    linear_mfma<<<1152, 256, 0, stream>>>(actB, vwp, vb, actA);                 // v
    attn_mfma<<<dim3(144, 4, 8), 256, 0, stream>>>(fgb, awb, abv, Abuf);
    attn_fold<<<dim3(288, 8), 128, 0, stream>>>(Abuf, actA, actB);              // folded
    linear_mfma<<<1152, 256, 0, stream>>>(actB, pwp, pb, actA);                 // p
    conv_gemm<128, false><<<dim3(72, 8), 256, 0, stream>>>(actA, w3p, bn3g, bn3b, actB);
    conv_gemm<128, true><<<dim3(72, 8), 256, 0, stream>>>(actB, w4p, bn4g, bn4b, d_out);
}